// Round 2
// baseline (4942.550 us; speedup 1.0000x reference)
//
#include <hip/hip_runtime.h>
#include <hip/hip_bf16.h>
#include <math.h>

#define HID     2560
#define D_INNER 8192
#define NG      32
#define D_SSM   4096
#define KCONV   4
#define HD      128
#define DS      64
#define LSEQ    1024
#define EPS_RMS 1e-6f

__device__ __forceinline__ float siluf(float x) { return x / (1.f + expf(-x)); }

// C[M,N] = A[M,K] @ B[N,K]^T, all f32.
// 64x64 tile, BK=16, 256 threads, 4x4 micro-tile. M%64==0, K%16==0 assumed.
__global__ __launch_bounds__(256)
void gemm_bt(const float* __restrict__ A, const float* __restrict__ B,
             float* __restrict__ C, int M, int N, int Kd) {
    __shared__ float As[64][17];
    __shared__ float Bs[64][17];
    const int tid = threadIdx.x;
    const int tx = tid & 15, ty = tid >> 4;
    const int m0 = blockIdx.y * 64, n0 = blockIdx.x * 64;

    float acc[4][4] = {};

    for (int k0 = 0; k0 < Kd; k0 += 16) {
        #pragma unroll
        for (int r = 0; r < 4; r++) {
            int idx = tid + r * 256;          // 0..1023 over 64x16
            int row = idx >> 4, col = idx & 15;
            As[row][col] = A[(size_t)(m0 + row) * Kd + k0 + col];
        }
        #pragma unroll
        for (int r = 0; r < 4; r++) {
            int idx = tid + r * 256;
            int row = idx >> 4, col = idx & 15;
            int n = n0 + row;
            Bs[row][col] = (n < N) ? B[(size_t)n * Kd + k0 + col] : 0.f;
        }
        __syncthreads();
        #pragma unroll
        for (int k = 0; k < 16; k++) {
            float a[4], b[4];
            #pragma unroll
            for (int i = 0; i < 4; i++) a[i] = As[ty + 16 * i][k];
            #pragma unroll
            for (int j = 0; j < 4; j++) b[j] = Bs[tx + 16 * j][k];
            #pragma unroll
            for (int i = 0; i < 4; i++)
                #pragma unroll
                for (int j = 0; j < 4; j++) acc[i][j] += a[i] * b[j];
        }
        __syncthreads();
    }

    #pragma unroll
    for (int i = 0; i < 4; i++) {
        int m = m0 + ty + 16 * i;
        #pragma unroll
        for (int j = 0; j < 4; j++) {
            int n = n0 + tx + 16 * j;
            if (n < N) C[(size_t)m * N + n] = acc[i][j];
        }
    }
}

// causal depthwise conv (K=4, left pad 3) + SiLU.  [L, D_INNER] f32 -> f32
__global__ __launch_bounds__(256)
void conv_silu(const float* __restrict__ xBC, const float* __restrict__ conv_w,
               float* __restrict__ out) {
    int idx = blockIdx.x * 256 + threadIdx.x;
    if (idx >= LSEQ * D_INNER) return;
    int t = idx / D_INNER, c = idx - t * D_INNER;
    float acc = 0.f;
    #pragma unroll
    for (int k = 0; k < KCONV; k++) {
        int tt = t - (KCONV - 1) + k;
        if (tt >= 0) acc += xBC[(size_t)tt * D_INNER + c] * conv_w[c * KCONV + k];
    }
    out[idx] = siluf(acc);
}

// Sequential SSM scan + fused per-head RMSNorm + SiLU(z) gating.
// One block per group (32 blocks), 256 threads. Thread owns h[hd][s0..s0+31],
// hd = tid>>1, s0 = (tid&1)*32.
__global__ __launch_bounds__(256)
void ssm_scan(const float* __restrict__ xc,     // [L, D_INNER] conv+silu output
              const float* __restrict__ dt_in,  // [L, NG]
              const float* __restrict__ D_in,   // [L, NG]
              const float* __restrict__ z,      // [L, D_SSM]
              const float* __restrict__ A_log, const float* __restrict__ dt_bias,
              const float* __restrict__ norm_w,
              float* __restrict__ y_out) {      // [L, D_SSM] gated
    const int g = blockIdx.x;
    const int tid = threadIdx.x;
    const int hd = tid >> 1;
    const int s0 = (tid & 1) * 32;

    const float A    = -expf(A_log[g]);
    const float bias = dt_bias[g];
    const float nw   = norm_w[hd];

    float h[32];
    #pragma unroll
    for (int i = 0; i < 32; i++) h[i] = 0.f;

    __shared__ float sx[HD], sB[DS], sC[DS], red[4];
    __shared__ float ssum;

    for (int t = 0; t < LSEQ; t++) {
        const float* row = xc + (size_t)t * D_INNER;
        if (tid < 128)      sx[tid]       = row[g * HD + tid];
        else if (tid < 192) sB[tid - 128] = row[D_SSM + g * DS + (tid - 128)];
        else                sC[tid - 192] = row[D_SSM + NG * DS + g * DS + (tid - 192)];
        __syncthreads();

        float dtr = dt_in[t * NG + g] + bias;
        float dt = (dtr > 20.f) ? dtr : log1pf(expf(dtr));
        float dA = expf(dt * A);
        float xv = sx[hd];
        float coef = dt * xv;

        float p = 0.f;
        #pragma unroll
        for (int s = 0; s < 32; s++) {
            h[s] = dA * h[s] + coef * sB[s0 + s];
            p += h[s] * sC[s0 + s];
        }
        p += __shfl_xor(p, 1);
        float y = p + D_in[t * NG + g] * xv;

        // RMSNorm over the 128 hd values of this head (== group)
        float c2 = (tid & 1) ? 0.f : y * y;
        #pragma unroll
        for (int off = 32; off; off >>= 1) c2 += __shfl_down(c2, off);
        if ((tid & 63) == 0) red[tid >> 6] = c2;
        __syncthreads();
        if (tid == 0) ssum = red[0] + red[1] + red[2] + red[3];
        __syncthreads();
        float scale = rsqrtf(ssum * (1.f / HD) + EPS_RMS);

        if ((tid & 1) == 0) {
            float zv = z[(size_t)t * D_SSM + g * HD + hd];
            y_out[(size_t)t * D_SSM + g * HD + hd] = y * scale * nw * siluf(zv);
        }
        __syncthreads();   // protect sx/sB/sC/ssum before next step
    }
}

extern "C" void kernel_launch(void* const* d_in, const int* in_sizes, int n_in,
                              void* d_out, int out_size, void* d_ws, size_t ws_size,
                              hipStream_t stream) {
    const float* hs      = (const float*)d_in[0];
    const float* W_qkv   = (const float*)d_in[1];
    const float* W_z     = (const float*)d_in[2];
    const float* W_a     = (const float*)d_in[3];
    const float* W_b     = (const float*)d_in[4];
    const float* conv_w  = (const float*)d_in[5];
    const float* W_out   = (const float*)d_in[6];
    const float* norm_w  = (const float*)d_in[7];
    const float* A_log   = (const float*)d_in[8];
    const float* dt_bias = (const float*)d_in[9];
    float* out = (float*)d_out;

    float* ws    = (float*)d_ws;
    float* xconv = ws;                                    // [L, D_INNER]  8.39M
    float* zbuf  = xconv + (size_t)LSEQ * D_INNER;        // [L, D_SSM]    4.19M
    float* dtbuf = zbuf  + (size_t)LSEQ * D_SSM;          // [L, NG]
    float* Dbuf  = dtbuf + (size_t)LSEQ * NG;             // [L, NG]
    float* xBC   = Dbuf  + (size_t)LSEQ * NG;             // [L, D_INNER]  8.39M
    float* yg    = xBC;   // alias: xBC dead after conv_silu; yg is [L, D_SSM]

    dim3 blk(256);

    // projections
    gemm_bt<<<dim3(D_INNER / 64, LSEQ / 64), blk, 0, stream>>>(
        hs, W_qkv, xBC, LSEQ, D_INNER, HID);
    gemm_bt<<<dim3(D_SSM / 64, LSEQ / 64), blk, 0, stream>>>(
        hs, W_z, zbuf, LSEQ, D_SSM, HID);
    gemm_bt<<<dim3(1, LSEQ / 64), blk, 0, stream>>>(
        hs, W_b, dtbuf, LSEQ, NG, HID);   // dt_input = h @ W_b^T
    gemm_bt<<<dim3(1, LSEQ / 64), blk, 0, stream>>>(
        hs, W_a, Dbuf, LSEQ, NG, HID);    // D_input  = h @ W_a^T

    // depthwise causal conv + silu
    conv_silu<<<dim3((LSEQ * D_INNER) / 256), blk, 0, stream>>>(xBC, conv_w, xconv);

    // sequential scan + RMSNorm + gating (writes yg, which aliases dead xBC)
    ssm_scan<<<dim3(NG), blk, 0, stream>>>(xconv, dtbuf, Dbuf, zbuf,
                                           A_log, dt_bias, norm_w, yg);

    // out = y_gated @ W_out^T
    gemm_bt<<<dim3(HID / 64, LSEQ / 64), blk, 0, stream>>>(
        yg, W_out, out, LSEQ, HID, D_SSM);
}

// Round 3
// 2831.045 us; speedup vs baseline: 1.7458x; 1.7458x over previous
//
#include <hip/hip_runtime.h>
#include <hip/hip_bf16.h>
#include <math.h>

#define HID     2560
#define D_INNER 8192
#define NG      32
#define D_SSM   4096
#define KCONV   4
#define HD      128
#define DS      64
#define LSEQ    1024
#define LC      64
#define NC      (LSEQ / LC)
#define EPS_RMS 1e-6f

__device__ __forceinline__ float siluf(float x) { return x / (1.f + expf(-x)); }

// ---------------- GEMM: C[M,N] = A[M,K] @ B[N,K]^T, f32 ----------------
__global__ __launch_bounds__(256)
void gemm_bt(const float* __restrict__ A, const float* __restrict__ B,
             float* __restrict__ C, int M, int N, int Kd) {
    __shared__ float As[64][17];
    __shared__ float Bs[64][17];
    const int tid = threadIdx.x;
    const int tx = tid & 15, ty = tid >> 4;
    const int m0 = blockIdx.y * 64, n0 = blockIdx.x * 64;

    float acc[4][4] = {};

    for (int k0 = 0; k0 < Kd; k0 += 16) {
        #pragma unroll
        for (int r = 0; r < 4; r++) {
            int idx = tid + r * 256;
            int row = idx >> 4, col = idx & 15;
            As[row][col] = A[(size_t)(m0 + row) * Kd + k0 + col];
        }
        #pragma unroll
        for (int r = 0; r < 4; r++) {
            int idx = tid + r * 256;
            int row = idx >> 4, col = idx & 15;
            int n = n0 + row;
            Bs[row][col] = (n < N) ? B[(size_t)n * Kd + k0 + col] : 0.f;
        }
        __syncthreads();
        #pragma unroll
        for (int k = 0; k < 16; k++) {
            float a[4], b[4];
            #pragma unroll
            for (int i = 0; i < 4; i++) a[i] = As[ty + 16 * i][k];
            #pragma unroll
            for (int j = 0; j < 4; j++) b[j] = Bs[tx + 16 * j][k];
            #pragma unroll
            for (int i = 0; i < 4; i++)
                #pragma unroll
                for (int j = 0; j < 4; j++) acc[i][j] += a[i] * b[j];
        }
        __syncthreads();
    }

    #pragma unroll
    for (int i = 0; i < 4; i++) {
        int m = m0 + ty + 16 * i;
        #pragma unroll
        for (int j = 0; j < 4; j++) {
            int n = n0 + tx + 16 * j;
            if (n < N) C[(size_t)m * N + n] = acc[i][j];
        }
    }
}

// ---------------- conv (K=4 causal) + SiLU ----------------
__global__ __launch_bounds__(256)
void conv_silu(const float* __restrict__ xBC, const float* __restrict__ conv_w,
               float* __restrict__ out) {
    int idx = blockIdx.x * 256 + threadIdx.x;
    if (idx >= LSEQ * D_INNER) return;
    int t = idx / D_INNER, c = idx - t * D_INNER;
    float acc = 0.f;
    #pragma unroll
    for (int k = 0; k < KCONV; k++) {
        int tt = t - (KCONV - 1) + k;
        if (tt >= 0) acc += xBC[(size_t)tt * D_INNER + c] * conv_w[c * KCONV + k];
    }
    out[idx] = siluf(acc);
}

// ---------------- S1: softplus(dt)+cumsum -> dt_soft [NG,L], S [NG,L], E [NG,NC] ----
__global__ __launch_bounds__(1024)
void dt_scan(const float* __restrict__ dt_in,   // [L,NG] raw
             const float* __restrict__ A_log, const float* __restrict__ dt_bias,
             float* __restrict__ dt_soft, float* __restrict__ Sbuf,
             float* __restrict__ Ebuf) {
    const int g = blockIdx.x, t = threadIdx.x;
    __shared__ float buf0[LSEQ], buf1[LSEQ];
    float dtr = dt_in[t * NG + g] + dt_bias[g];
    float dt = (dtr > 20.f) ? dtr : log1pf(expf(dtr));
    dt_soft[g * LSEQ + t] = dt;
    buf0[t] = dt;
    __syncthreads();
    float* src = buf0; float* dst = buf1;
    for (int off = 1; off < LSEQ; off <<= 1) {
        float v = src[t];
        if (t >= off) v += src[t - off];
        dst[t] = v;
        __syncthreads();
        float* tmp = src; src = dst; dst = tmp;
    }
    float A = -expf(A_log[g]);
    float S = A * src[t];
    Sbuf[g * LSEQ + t] = S;
    if ((t & (LC - 1)) == LC - 1) Ebuf[g * NC + (t >> 6)] = S;
}

// ---------------- S2: chunk states Sc[g,c][s,h] = sum_tau e^{E_c-S_tau} dt_tau B[tau,s] x[tau,h]
__global__ __launch_bounds__(256)
void chunk_state(const float* __restrict__ xc, const float* __restrict__ dt_soft,
                 const float* __restrict__ Sbuf, const float* __restrict__ Ebuf,
                 float* __restrict__ Sc) {
    const int g = blockIdx.x, c = blockIdx.y;
    const int tid = threadIdx.x;
    const int t0 = c * LC;
    __shared__ __align__(16) float wB[LC][DS];   // 16K
    __shared__ float Xs[LC][HD];                  // 32K
    __shared__ float sw[LC];

    if (tid < LC) {
        float Ec = Ebuf[g * NC + c];
        sw[tid] = expf(Ec - Sbuf[g * LSEQ + t0 + tid]) * dt_soft[g * LSEQ + t0 + tid];
    }
    __syncthreads();
    for (int i = tid; i < LC * DS; i += 256) {
        int r = i >> 6, s = i & 63;
        wB[r][s] = sw[r] * xc[(size_t)(t0 + r) * D_INNER + D_SSM + g * DS + s];
    }
    for (int i = tid; i < LC * HD; i += 256) {
        int r = i >> 7, h = i & 127;
        Xs[r][h] = xc[(size_t)(t0 + r) * D_INNER + g * HD + h];
    }
    __syncthreads();

    const int h = tid & 127, sh = (tid >> 7) * 32;
    float acc[32];
    #pragma unroll
    for (int j = 0; j < 32; j++) acc[j] = 0.f;
    for (int r = 0; r < LC; r++) {
        float xv = Xs[r][h];
        const float4* wrow = (const float4*)&wB[r][sh];
        #pragma unroll
        for (int q = 0; q < 8; q++) {
            float4 w4 = wrow[q];
            acc[4*q+0] += w4.x * xv;
            acc[4*q+1] += w4.y * xv;
            acc[4*q+2] += w4.z * xv;
            acc[4*q+3] += w4.w * xv;
        }
    }
    float* out = Sc + (size_t)(g * NC + c) * DS * HD;
    #pragma unroll
    for (int j = 0; j < 32; j++) out[(size_t)(sh + j) * HD + h] = acc[j];
}

// ---------------- S3: prefix over chunks: Hbuf[g,c] = state entering chunk c ----
__global__ __launch_bounds__(256)
void chunk_prefix(const float* __restrict__ Sc, const float* __restrict__ Ebuf,
                  float* __restrict__ Hbuf) {
    const int g = blockIdx.y;
    const int e = blockIdx.x * 256 + threadIdx.x;   // [0, DS*HD)
    float H = 0.f, Eprev = 0.f;
    for (int c = 0; c < NC; c++) {
        size_t base = (size_t)(g * NC + c) * DS * HD;
        Hbuf[base + e] = H;
        float Ec = Ebuf[g * NC + c];
        H = expf(Ec - Eprev) * H + Sc[base + e];
        Eprev = Ec;
    }
}

// ---------------- S4: per-chunk output + RMSNorm + SiLU(z) gating ----------------
__global__ __launch_bounds__(256)
void chunk_output(const float* __restrict__ xc, const float* __restrict__ dt_soft,
                  const float* __restrict__ Sbuf, const float* __restrict__ Ebuf,
                  const float* __restrict__ D_in, const float* __restrict__ Hbuf,
                  const float* __restrict__ z, const float* __restrict__ norm_w,
                  float* __restrict__ yg) {
    const int g = blockIdx.x, c = blockIdx.y;
    const int tid = threadIdx.x;
    const int t0 = c * LC;

    // 16384 floats = 64KB exactly: CT[64][64] | BW[64][64] | Xs[64][128]
    __shared__ __align__(16) float smem[4096 + 4096 + 8192];
    float* CT = smem;            // CT[s*64 + t] = C_t[s]
    float* BW = smem + 4096;     // B[tau*64+s], later WT[tau*64+t]
    float* Xs = smem + 8192;     // x[t*128+h], later y[t*128+h]
    float* red = smem;           // alias CT (dead after inter): red[t*4+q]
    float* sscale = smem + 256;  // alias CT

    // stage
    for (int i = tid; i < LC * DS; i += 256) {
        int t = i >> 6, s = i & 63;
        CT[s * LC + t] = xc[(size_t)(t0 + t) * D_INNER + D_SSM + NG * DS + g * DS + s];
        BW[t * DS + s] = xc[(size_t)(t0 + t) * D_INNER + D_SSM + g * DS + s];
    }
    for (int i = tid; i < LC * HD; i += 256) {
        int t = i >> 7, h = i & 127;
        Xs[t * HD + h] = xc[(size_t)(t0 + t) * D_INNER + g * HD + h];
    }
    __syncthreads();

    // G[t,tau] = C_t . B_tau ; thread: t = tid&63, tau = (tid>>6) + 4k
    {
        const int t = tid & 63, tau0 = tid >> 6;
        float Greg[16];
        #pragma unroll
        for (int k = 0; k < 16; k++) Greg[k] = 0.f;
        for (int s = 0; s < DS; s++) {
            float cv = CT[s * LC + t];
            #pragma unroll
            for (int k = 0; k < 16; k++) Greg[k] += cv * BW[(tau0 + 4 * k) * DS + s];
        }
        __syncthreads();   // all G reads of B done
        float St = Sbuf[g * LSEQ + t0 + t];
        #pragma unroll
        for (int k = 0; k < 16; k++) {
            int tau = tau0 + 4 * k;
            float w = 0.f;
            if (tau <= t)
                w = expf(St - Sbuf[g * LSEQ + t0 + tau]) *
                    dt_soft[g * LSEQ + t0 + tau] * Greg[k];
            BW[tau * LC + t] = w;   // WT[tau][t]
        }
    }
    __syncthreads();

    // y: thread h = tid&127, t range tb..tb+31
    const int h = tid & 127, tb = (tid >> 7) * 32;
    float y[32], T[32];
    #pragma unroll
    for (int j = 0; j < 32; j++) { y[j] = 0.f; T[j] = 0.f; }

    // intra: y[j] += WT[tau][tb+j] * x[tau][h]
    for (int tau = 0; tau < LC; tau++) {
        float xv = Xs[tau * HD + h];
        const float4* wrow = (const float4*)&BW[tau * LC + tb];
        #pragma unroll
        for (int q = 0; q < 8; q++) {
            float4 w4 = wrow[q];
            y[4*q+0] += w4.x * xv;
            y[4*q+1] += w4.y * xv;
            y[4*q+2] += w4.z * xv;
            y[4*q+3] += w4.w * xv;
        }
    }
    // inter: T[j] = sum_s C[tb+j][s] * H[s][h]
    {
        const float* Hg = Hbuf + (size_t)(g * NC + c) * DS * HD;
        for (int s = 0; s < DS; s++) {
            float Hv = Hg[(size_t)s * HD + h];
            const float* crow = &CT[s * LC + tb];
            #pragma unroll
            for (int j = 0; j < 32; j++) T[j] += crow[j] * Hv;
        }
    }
    // combine
    float Eprev = (c > 0) ? Ebuf[g * NC + c - 1] : 0.f;
    #pragma unroll
    for (int j = 0; j < 32; j++) {
        int t = tb + j;
        float St = Sbuf[g * LSEQ + t0 + t];
        float Dv = D_in[(size_t)(t0 + t) * NG + g];
        y[j] += expf(St - Eprev) * T[j] + Dv * Xs[t * HD + h];
    }
    __syncthreads();   // all reads of Xs / CT done
    #pragma unroll
    for (int j = 0; j < 32; j++) Xs[(tb + j) * HD + h] = y[j];
    __syncthreads();

    // RMSNorm over h (head dim = 128) per t
    {
        int t = tid >> 2, q = tid & 3;
        float p = 0.f;
        for (int i = 0; i < 32; i++) {
            float v = Xs[t * HD + q * 32 + i];
            p += v * v;
        }
        red[t * 4 + q] = p;
    }
    __syncthreads();
    if (tid < LC) {
        float s2 = red[tid*4] + red[tid*4+1] + red[tid*4+2] + red[tid*4+3];
        sscale[tid] = rsqrtf(s2 * (1.f / HD) + EPS_RMS);
    }
    __syncthreads();

    float nw = norm_w[h];
    #pragma unroll
    for (int j = 0; j < 32; j++) {
        int t = tb + j;
        size_t idx = (size_t)(t0 + t) * D_SSM + g * HD + h;
        float zv = z[idx];
        yg[idx] = y[j] * sscale[t] * nw * siluf(zv);
    }
}

extern "C" void kernel_launch(void* const* d_in, const int* in_sizes, int n_in,
                              void* d_out, int out_size, void* d_ws, size_t ws_size,
                              hipStream_t stream) {
    const float* hs      = (const float*)d_in[0];
    const float* W_qkv   = (const float*)d_in[1];
    const float* W_z     = (const float*)d_in[2];
    const float* W_a     = (const float*)d_in[3];
    const float* W_b     = (const float*)d_in[4];
    const float* conv_w  = (const float*)d_in[5];
    const float* W_out   = (const float*)d_in[6];
    const float* norm_w  = (const float*)d_in[7];
    const float* A_log   = (const float*)d_in[8];
    const float* dt_bias = (const float*)d_in[9];
    float* out = (float*)d_out;

    float* ws      = (float*)d_ws;
    float* xconv   = ws;                                   // L*D_INNER
    float* zbuf    = xconv + (size_t)LSEQ * D_INNER;       // L*D_SSM (also yg)
    float* dtbuf   = zbuf + (size_t)LSEQ * D_SSM;          // L*NG raw
    float* Dbuf    = dtbuf + (size_t)LSEQ * NG;            // L*NG
    float* dt_soft = Dbuf + (size_t)LSEQ * NG;             // NG*L
    float* Sbuf    = dt_soft + (size_t)NG * LSEQ;          // NG*L
    float* Ebuf    = Sbuf + (size_t)NG * LSEQ;             // NG*NC
    float* xBC     = Ebuf + NG * NC;                       // L*D_INNER (reused)
    float* Sc      = xBC;                                  // NG*NC*DS*HD
    float* Hbuf    = xBC + (size_t)NG * NC * DS * HD;      // NG*NC*DS*HD
    float* yg      = zbuf;                                 // in-place over z

    dim3 blk(256);

    gemm_bt<<<dim3(D_INNER / 64, LSEQ / 64), blk, 0, stream>>>(
        hs, W_qkv, xBC, LSEQ, D_INNER, HID);
    gemm_bt<<<dim3(D_SSM / 64, LSEQ / 64), blk, 0, stream>>>(
        hs, W_z, zbuf, LSEQ, D_SSM, HID);
    gemm_bt<<<dim3(1, LSEQ / 64), blk, 0, stream>>>(
        hs, W_b, dtbuf, LSEQ, NG, HID);
    gemm_bt<<<dim3(1, LSEQ / 64), blk, 0, stream>>>(
        hs, W_a, Dbuf, LSEQ, NG, HID);

    conv_silu<<<dim3((LSEQ * D_INNER) / 256), blk, 0, stream>>>(xBC, conv_w, xconv);

    dt_scan<<<dim3(NG), dim3(1024), 0, stream>>>(dtbuf, A_log, dt_bias,
                                                 dt_soft, Sbuf, Ebuf);
    chunk_state<<<dim3(NG, NC), blk, 0, stream>>>(xconv, dt_soft, Sbuf, Ebuf, Sc);
    chunk_prefix<<<dim3(DS * HD / 256, NG), blk, 0, stream>>>(Sc, Ebuf, Hbuf);
    chunk_output<<<dim3(NG, NC), blk, 0, stream>>>(xconv, dt_soft, Sbuf, Ebuf,
                                                   Dbuf, Hbuf, zbuf, norm_w, yg);

    gemm_bt<<<dim3(HID / 64, LSEQ / 64), blk, 0, stream>>>(
        yg, W_out, out, LSEQ, HID, D_SSM);
}

// Round 4
// 1349.568 us; speedup vs baseline: 3.6623x; 2.0977x over previous
//
#include <hip/hip_runtime.h>
#include <hip/hip_bf16.h>
#include <math.h>

#define HID     2560
#define D_INNER 8192
#define NG      32
#define D_SSM   4096
#define KCONV   4
#define HD      128
#define DS      64
#define LSEQ    1024
#define LC      64
#define NC      (LSEQ / LC)
#define EPS_RMS 1e-6f

typedef short bf16x8 __attribute__((ext_vector_type(8)));
typedef float f32x4 __attribute__((ext_vector_type(4)));

__device__ __forceinline__ float siluf(float x) { return x / (1.f + expf(-x)); }

__device__ __forceinline__ unsigned short f2bf(float x) {
    __hip_bfloat16 b = __float2bfloat16(x);
    return *reinterpret_cast<unsigned short*>(&b);
}
__device__ __forceinline__ float bf2f(unsigned short u) {
    union { unsigned int i; float f; } v;
    v.i = ((unsigned int)u) << 16;
    return v.f;
}

__device__ __forceinline__ void async16(const ushort* g, ushort* l) {
    __builtin_amdgcn_global_load_lds(
        (const __attribute__((address_space(1))) unsigned int*)g,
        (__attribute__((address_space(3))) unsigned int*)l, 16, 0, 0);
}

// ---------------- f32 -> (hi, lo) bf16 planes ----------------
__global__ __launch_bounds__(256)
void split_cvt(const float4* __restrict__ in, ushort4* __restrict__ hi,
               ushort4* __restrict__ lo, int n4) {
    int i = blockIdx.x * 256 + threadIdx.x;
    if (i >= n4) return;
    float4 v = in[i];
    ushort4 h, l;
    h.x = f2bf(v.x); l.x = f2bf(v.x - bf2f(h.x));
    h.y = f2bf(v.y); l.y = f2bf(v.y - bf2f(h.y));
    h.z = f2bf(v.z); l.z = f2bf(v.z - bf2f(h.z));
    h.w = f2bf(v.w); l.w = f2bf(v.w - bf2f(h.w));
    hi[i] = h; lo[i] = l;
}

// ---------------- MFMA GEMM: C[M,N] = A[M,K] @ B[N,K]^T (split bf16, ~f32 acc) ----
// A,B given as hi/lo bf16 planes, row-major, lda=ldb=K. Grid: (N/128, M/128).
// 256 threads = 4 waves; wave computes 64x64 via 4x4 tiles of 16x16x32 MFMA.
__global__ __launch_bounds__(256)
void gemm_mfma_split(const ushort* __restrict__ Ah, const ushort* __restrict__ Al,
                     const ushort* __restrict__ Bh, const ushort* __restrict__ Bl,
                     float* __restrict__ C, int K, int ldc) {
    __shared__ ushort sA[2][128][32];   // 16 KB
    __shared__ ushort sB[2][128][32];   // 16 KB
    const int tid  = threadIdx.x;
    const int wave = tid >> 6, lane = tid & 63;
    const int m0 = blockIdx.y * 128, n0 = blockIdx.x * 128;
    const int wm = (wave >> 1) * 64, wn = (wave & 1) * 64;
    const int srow = lane >> 2;          // 0..15: row within a 16-row group
    const int scol = (lane & 3) * 8;     // 0,8,16,24: elem offset (16B chunks)

    f32x4 acc[4][4];
    #pragma unroll
    for (int i = 0; i < 4; i++)
        #pragma unroll
        for (int j = 0; j < 4; j++) acc[i][j] = (f32x4){0.f, 0.f, 0.f, 0.f};

    const int r0 = wave * 32;   // this wave stages tile rows r0..r0+31

    for (int k0 = 0; k0 < K; k0 += 32) {
        #pragma unroll
        for (int i = 0; i < 2; i++) {
            int rt = r0 + i * 16;          // group base row (wave-uniform)
            int rg = rt + srow;            // this lane's row
            size_t goffA = (size_t)(m0 + rg) * K + k0 + scol;
            size_t goffB = (size_t)(n0 + rg) * K + k0 + scol;
            async16(Ah + goffA, &sA[0][rt][0]);
            async16(Al + goffA, &sA[1][rt][0]);
            async16(Bh + goffB, &sB[0][rt][0]);
            async16(Bl + goffB, &sB[1][rt][0]);
        }
        __syncthreads();

        const int fr = lane & 15, fk = (lane >> 4) * 8;
        bf16x8 a[2][4], b[2][4];
        #pragma unroll
        for (int t = 0; t < 4; t++) {
            a[0][t] = *(const bf16x8*)&sA[0][wm + t * 16 + fr][fk];
            a[1][t] = *(const bf16x8*)&sA[1][wm + t * 16 + fr][fk];
            b[0][t] = *(const bf16x8*)&sB[0][wn + t * 16 + fr][fk];
            b[1][t] = *(const bf16x8*)&sB[1][wn + t * 16 + fr][fk];
        }
        #pragma unroll
        for (int mt = 0; mt < 4; mt++)
            #pragma unroll
            for (int nt = 0; nt < 4; nt++) {
                acc[mt][nt] = __builtin_amdgcn_mfma_f32_16x16x32_bf16(
                    a[0][mt], b[0][nt], acc[mt][nt], 0, 0, 0);
                acc[mt][nt] = __builtin_amdgcn_mfma_f32_16x16x32_bf16(
                    a[0][mt], b[1][nt], acc[mt][nt], 0, 0, 0);
                acc[mt][nt] = __builtin_amdgcn_mfma_f32_16x16x32_bf16(
                    a[1][mt], b[0][nt], acc[mt][nt], 0, 0, 0);
            }
        __syncthreads();
    }

    const int fr = lane & 15, rq = (lane >> 4) * 4;
    #pragma unroll
    for (int mt = 0; mt < 4; mt++)
        #pragma unroll
        for (int nt = 0; nt < 4; nt++) {
            int col = n0 + wn + nt * 16 + fr;
            int row = m0 + wm + mt * 16 + rq;
            #pragma unroll
            for (int r = 0; r < 4; r++)
                C[(size_t)(row + r) * ldc + col] = acc[mt][nt][r];
        }
}

// ---------------- small f32 GEMM (dt/D projections, N=32) ----------------
__global__ __launch_bounds__(256)
void gemm_bt(const float* __restrict__ A, const float* __restrict__ B,
             float* __restrict__ C, int M, int N, int Kd) {
    __shared__ float As[64][17];
    __shared__ float Bs[64][17];
    const int tid = threadIdx.x;
    const int tx = tid & 15, ty = tid >> 4;
    const int m0 = blockIdx.y * 64, n0 = blockIdx.x * 64;

    float acc[4][4] = {};

    for (int k0 = 0; k0 < Kd; k0 += 16) {
        #pragma unroll
        for (int r = 0; r < 4; r++) {
            int idx = tid + r * 256;
            int row = idx >> 4, col = idx & 15;
            As[row][col] = A[(size_t)(m0 + row) * Kd + k0 + col];
        }
        #pragma unroll
        for (int r = 0; r < 4; r++) {
            int idx = tid + r * 256;
            int row = idx >> 4, col = idx & 15;
            int n = n0 + row;
            Bs[row][col] = (n < N) ? B[(size_t)n * Kd + k0 + col] : 0.f;
        }
        __syncthreads();
        #pragma unroll
        for (int k = 0; k < 16; k++) {
            float a[4], b[4];
            #pragma unroll
            for (int i = 0; i < 4; i++) a[i] = As[ty + 16 * i][k];
            #pragma unroll
            for (int j = 0; j < 4; j++) b[j] = Bs[tx + 16 * j][k];
            #pragma unroll
            for (int i = 0; i < 4; i++)
                #pragma unroll
                for (int j = 0; j < 4; j++) acc[i][j] += a[i] * b[j];
        }
        __syncthreads();
    }

    #pragma unroll
    for (int i = 0; i < 4; i++) {
        int m = m0 + ty + 16 * i;
        #pragma unroll
        for (int j = 0; j < 4; j++) {
            int n = n0 + tx + 16 * j;
            if (n < N) C[(size_t)m * N + n] = acc[i][j];
        }
    }
}

// ---------------- conv (K=4 causal) + SiLU ----------------
__global__ __launch_bounds__(256)
void conv_silu(const float* __restrict__ xBC, const float* __restrict__ conv_w,
               float* __restrict__ out) {
    int idx = blockIdx.x * 256 + threadIdx.x;
    if (idx >= LSEQ * D_INNER) return;
    int t = idx / D_INNER, c = idx - t * D_INNER;
    float acc = 0.f;
    #pragma unroll
    for (int k = 0; k < KCONV; k++) {
        int tt = t - (KCONV - 1) + k;
        if (tt >= 0) acc += xBC[(size_t)tt * D_INNER + c] * conv_w[c * KCONV + k];
    }
    out[idx] = siluf(acc);
}

// ---------------- S1: softplus(dt)+cumsum ----------------
__global__ __launch_bounds__(1024)
void dt_scan(const float* __restrict__ dt_in,
             const float* __restrict__ A_log, const float* __restrict__ dt_bias,
             float* __restrict__ dt_soft, float* __restrict__ Sbuf,
             float* __restrict__ Ebuf) {
    const int g = blockIdx.x, t = threadIdx.x;
    __shared__ float buf0[LSEQ], buf1[LSEQ];
    float dtr = dt_in[t * NG + g] + dt_bias[g];
    float dt = (dtr > 20.f) ? dtr : log1pf(expf(dtr));
    dt_soft[g * LSEQ + t] = dt;
    buf0[t] = dt;
    __syncthreads();
    float* src = buf0; float* dst = buf1;
    for (int off = 1; off < LSEQ; off <<= 1) {
        float v = src[t];
        if (t >= off) v += src[t - off];
        dst[t] = v;
        __syncthreads();
        float* tmp = src; src = dst; dst = tmp;
    }
    float A = -expf(A_log[g]);
    float S = A * src[t];
    Sbuf[g * LSEQ + t] = S;
    if ((t & (LC - 1)) == LC - 1) Ebuf[g * NC + (t >> 6)] = S;
}

// ---------------- S2: chunk states ----------------
__global__ __launch_bounds__(256)
void chunk_state(const float* __restrict__ xc, const float* __restrict__ dt_soft,
                 const float* __restrict__ Sbuf, const float* __restrict__ Ebuf,
                 float* __restrict__ Sc) {
    const int g = blockIdx.x, c = blockIdx.y;
    const int tid = threadIdx.x;
    const int t0 = c * LC;
    __shared__ __align__(16) float wB[LC][DS];
    __shared__ float Xs[LC][HD];
    __shared__ float sw[LC];

    if (tid < LC) {
        float Ec = Ebuf[g * NC + c];
        sw[tid] = expf(Ec - Sbuf[g * LSEQ + t0 + tid]) * dt_soft[g * LSEQ + t0 + tid];
    }
    __syncthreads();
    for (int i = tid; i < LC * DS; i += 256) {
        int r = i >> 6, s = i & 63;
        wB[r][s] = sw[r] * xc[(size_t)(t0 + r) * D_INNER + D_SSM + g * DS + s];
    }
    for (int i = tid; i < LC * HD; i += 256) {
        int r = i >> 7, h = i & 127;
        Xs[r][h] = xc[(size_t)(t0 + r) * D_INNER + g * HD + h];
    }
    __syncthreads();

    const int h = tid & 127, sh = (tid >> 7) * 32;
    float acc[32];
    #pragma unroll
    for (int j = 0; j < 32; j++) acc[j] = 0.f;
    for (int r = 0; r < LC; r++) {
        float xv = Xs[r][h];
        const float4* wrow = (const float4*)&wB[r][sh];
        #pragma unroll
        for (int q = 0; q < 8; q++) {
            float4 w4 = wrow[q];
            acc[4*q+0] += w4.x * xv;
            acc[4*q+1] += w4.y * xv;
            acc[4*q+2] += w4.z * xv;
            acc[4*q+3] += w4.w * xv;
        }
    }
    float* out = Sc + (size_t)(g * NC + c) * DS * HD;
    #pragma unroll
    for (int j = 0; j < 32; j++) out[(size_t)(sh + j) * HD + h] = acc[j];
}

// ---------------- S3: prefix over chunks ----------------
__global__ __launch_bounds__(256)
void chunk_prefix(const float* __restrict__ Sc, const float* __restrict__ Ebuf,
                  float* __restrict__ Hbuf) {
    const int g = blockIdx.y;
    const int e = blockIdx.x * 256 + threadIdx.x;
    float H = 0.f, Eprev = 0.f;
    for (int c = 0; c < NC; c++) {
        size_t base = (size_t)(g * NC + c) * DS * HD;
        Hbuf[base + e] = H;
        float Ec = Ebuf[g * NC + c];
        H = expf(Ec - Eprev) * H + Sc[base + e];
        Eprev = Ec;
    }
}

// ---------------- S4: per-chunk output + RMSNorm + SiLU(z), emits yg hi/lo bf16 ----
__global__ __launch_bounds__(256)
void chunk_output(const float* __restrict__ xc, const float* __restrict__ dt_soft,
                  const float* __restrict__ Sbuf, const float* __restrict__ Ebuf,
                  const float* __restrict__ D_in, const float* __restrict__ Hbuf,
                  const float* __restrict__ z, const float* __restrict__ norm_w,
                  ushort* __restrict__ ygH, ushort* __restrict__ ygL) {
    const int g = blockIdx.x, c = blockIdx.y;
    const int tid = threadIdx.x;
    const int t0 = c * LC;

    __shared__ __align__(16) float smem[4096 + 4096 + 8192];
    float* CT = smem;
    float* BW = smem + 4096;
    float* Xs = smem + 8192;
    float* red = smem;
    float* sscale = smem + 256;

    for (int i = tid; i < LC * DS; i += 256) {
        int t = i >> 6, s = i & 63;
        CT[s * LC + t] = xc[(size_t)(t0 + t) * D_INNER + D_SSM + NG * DS + g * DS + s];
        BW[t * DS + s] = xc[(size_t)(t0 + t) * D_INNER + D_SSM + g * DS + s];
    }
    for (int i = tid; i < LC * HD; i += 256) {
        int t = i >> 7, h = i & 127;
        Xs[t * HD + h] = xc[(size_t)(t0 + t) * D_INNER + g * HD + h];
    }
    __syncthreads();

    {
        const int t = tid & 63, tau0 = tid >> 6;
        float Greg[16];
        #pragma unroll
        for (int k = 0; k < 16; k++) Greg[k] = 0.f;
        for (int s = 0; s < DS; s++) {
            float cv = CT[s * LC + t];
            #pragma unroll
            for (int k = 0; k < 16; k++) Greg[k] += cv * BW[(tau0 + 4 * k) * DS + s];
        }
        __syncthreads();
        float St = Sbuf[g * LSEQ + t0 + t];
        #pragma unroll
        for (int k = 0; k < 16; k++) {
            int tau = tau0 + 4 * k;
            float w = 0.f;
            if (tau <= t)
                w = expf(St - Sbuf[g * LSEQ + t0 + tau]) *
                    dt_soft[g * LSEQ + t0 + tau] * Greg[k];
            BW[tau * LC + t] = w;
        }
    }
    __syncthreads();

    const int h = tid & 127, tb = (tid >> 7) * 32;
    float y[32], T[32];
    #pragma unroll
    for (int j = 0; j < 32; j++) { y[j] = 0.f; T[j] = 0.f; }

    for (int tau = 0; tau < LC; tau++) {
        float xv = Xs[tau * HD + h];
        const float4* wrow = (const float4*)&BW[tau * LC + tb];
        #pragma unroll
        for (int q = 0; q < 8; q++) {
            float4 w4 = wrow[q];
            y[4*q+0] += w4.x * xv;
            y[4*q+1] += w4.y * xv;
            y[4*q+2] += w4.z * xv;
            y[4*q+3] += w4.w * xv;
        }
    }
    {
        const float* Hg = Hbuf + (size_t)(g * NC + c) * DS * HD;
        for (int s = 0; s < DS; s++) {
            float Hv = Hg[(size_t)s * HD + h];
            const float* crow = &CT[s * LC + tb];
            #pragma unroll
            for (int j = 0; j < 32; j++) T[j] += crow[j] * Hv;
        }
    }
    float Eprev = (c > 0) ? Ebuf[g * NC + c - 1] : 0.f;
    #pragma unroll
    for (int j = 0; j < 32; j++) {
        int t = tb + j;
        float St = Sbuf[g * LSEQ + t0 + t];
        float Dv = D_in[(size_t)(t0 + t) * NG + g];
        y[j] += expf(St - Eprev) * T[j] + Dv * Xs[t * HD + h];
    }
    __syncthreads();
    #pragma unroll
    for (int j = 0; j < 32; j++) Xs[(tb + j) * HD + h] = y[j];
    __syncthreads();

    {
        int t = tid >> 2, q = tid & 3;
        float p = 0.f;
        for (int i = 0; i < 32; i++) {
            float v = Xs[t * HD + q * 32 + i];
            p += v * v;
        }
        red[t * 4 + q] = p;
    }
    __syncthreads();
    if (tid < LC) {
        float s2 = red[tid*4] + red[tid*4+1] + red[tid*4+2] + red[tid*4+3];
        sscale[tid] = rsqrtf(s2 * (1.f / HD) + EPS_RMS);
    }
    __syncthreads();

    float nw = norm_w[h];
    #pragma unroll
    for (int j = 0; j < 32; j++) {
        int t = tb + j;
        size_t idx = (size_t)(t0 + t) * D_SSM + g * HD + h;
        float zv = z[idx];
        float val = y[j] * sscale[t] * nw * siluf(zv);
        unsigned short hb = f2bf(val);
        ygH[idx] = hb;
        ygL[idx] = f2bf(val - bf2f(hb));
    }
}

extern "C" void kernel_launch(void* const* d_in, const int* in_sizes, int n_in,
                              void* d_out, int out_size, void* d_ws, size_t ws_size,
                              hipStream_t stream) {
    const float* hs      = (const float*)d_in[0];
    const float* W_qkv   = (const float*)d_in[1];
    const float* W_z     = (const float*)d_in[2];
    const float* W_a     = (const float*)d_in[3];
    const float* W_b     = (const float*)d_in[4];
    const float* conv_w  = (const float*)d_in[5];
    const float* W_out   = (const float*)d_in[6];
    const float* norm_w  = (const float*)d_in[7];
    const float* A_log   = (const float*)d_in[8];
    const float* dt_bias = (const float*)d_in[9];
    float* out = (float*)d_out;

    float* ws      = (float*)d_ws;
    float* xconv   = ws;                                   // 8388608
    float* zbuf    = xconv + (size_t)LSEQ * D_INNER;       // 4194304
    float* dtbuf   = zbuf + (size_t)LSEQ * D_SSM;          // 32768
    float* Dbuf    = dtbuf + (size_t)LSEQ * NG;            // 32768
    float* dt_soft = Dbuf + (size_t)LSEQ * NG;             // 32768
    float* Sbuf    = dt_soft + (size_t)NG * LSEQ;          // 32768
    float* Ebuf    = Sbuf + (size_t)NG * LSEQ;             // 512
    float* xBC     = Ebuf + NG * NC;                       // 8388608 (Sc+Hbuf alias)
    float* Sc      = xBC;
    float* Hbuf    = xBC + (size_t)NG * NC * DS * HD;
    ushort* hsH    = (ushort*)(xBC + (size_t)LSEQ * D_INNER);
    ushort* hsL    = hsH + (size_t)LSEQ * HID;             // 2621440 each
    ushort* WH     = hsL + (size_t)LSEQ * HID;             // 10485760 each
    ushort* WL     = WH + (size_t)4096 * HID;
    ushort* ygH    = WL + (size_t)4096 * HID;              // 4194304 each
    ushort* ygL    = ygH + (size_t)LSEQ * D_SSM;

    dim3 blk(256);
    const int nW4 = (4096 * HID) / 4;      // weight chunk, in float4s

    // hs -> hi/lo planes
    split_cvt<<<dim3((LSEQ * HID / 4 + 255) / 256), blk, 0, stream>>>(
        (const float4*)hs, (ushort4*)hsH, (ushort4*)hsL, LSEQ * HID / 4);

    // qkv GEMM in two N=4096 halves (weight plane buffer reuse)
    for (int half = 0; half < 2; half++) {
        split_cvt<<<dim3((nW4 + 255) / 256), blk, 0, stream>>>(
            (const float4*)(W_qkv + (size_t)half * 4096 * HID),
            (ushort4*)WH, (ushort4*)WL, nW4);
        gemm_mfma_split<<<dim3(4096 / 128, LSEQ / 128), blk, 0, stream>>>(
            hsH, hsL, WH, WL, xBC + half * 4096, HID, D_INNER);
    }

    // z GEMM
    split_cvt<<<dim3((nW4 + 255) / 256), blk, 0, stream>>>(
        (const float4*)W_z, (ushort4*)WH, (ushort4*)WL, nW4);
    gemm_mfma_split<<<dim3(D_SSM / 128, LSEQ / 128), blk, 0, stream>>>(
        hsH, hsL, WH, WL, zbuf, HID, D_SSM);

    // small projections (f32 vector path)
    gemm_bt<<<dim3(1, LSEQ / 64), blk, 0, stream>>>(hs, W_b, dtbuf, LSEQ, NG, HID);
    gemm_bt<<<dim3(1, LSEQ / 64), blk, 0, stream>>>(hs, W_a, Dbuf, LSEQ, NG, HID);

    conv_silu<<<dim3((LSEQ * D_INNER) / 256), blk, 0, stream>>>(xBC, conv_w, xconv);

    dt_scan<<<dim3(NG), dim3(1024), 0, stream>>>(dtbuf, A_log, dt_bias,
                                                 dt_soft, Sbuf, Ebuf);
    chunk_state<<<dim3(NG, NC), blk, 0, stream>>>(xconv, dt_soft, Sbuf, Ebuf, Sc);
    chunk_prefix<<<dim3(DS * HD / 256, NG), blk, 0, stream>>>(Sc, Ebuf, Hbuf);
    chunk_output<<<dim3(NG, NC), blk, 0, stream>>>(xconv, dt_soft, Sbuf, Ebuf,
                                                   Dbuf, Hbuf, zbuf, norm_w,
                                                   ygH, ygL);

    // out = yg @ W_out^T  (M=1024, N=2560, K=4096)
    split_cvt<<<dim3((nW4 + 255) / 256), blk, 0, stream>>>(
        (const float4*)W_out, (ushort4*)WH, (ushort4*)WL, nW4);
    gemm_mfma_split<<<dim3(HID / 128, LSEQ / 128), blk, 0, stream>>>(
        ygH, ygL, WH, WL, out, D_SSM, HID);
}

// Round 5
// 848.867 us; speedup vs baseline: 5.8225x; 1.5898x over previous
//
#include <hip/hip_runtime.h>
#include <hip/hip_bf16.h>
#include <math.h>

#define HID     2560
#define D_INNER 8192
#define NG      32
#define D_SSM   4096
#define KCONV   4
#define HD      128
#define DS      64
#define LSEQ    1024
#define LC      64
#define NC      (LSEQ / LC)
#define NZ      4224          // combined z(4096) + dt(32) + D(32) + pad(64)
#define EPS_RMS 1e-6f

typedef short bf16x8 __attribute__((ext_vector_type(8)));
typedef float f32x4 __attribute__((ext_vector_type(4)));

__device__ __forceinline__ float siluf(float x) { return x / (1.f + expf(-x)); }

__device__ __forceinline__ unsigned short f2bf(float x) {
    __hip_bfloat16 b = __float2bfloat16(x);
    return *reinterpret_cast<unsigned short*>(&b);
}
__device__ __forceinline__ float bf2f(unsigned short u) {
    union { unsigned int i; float f; } v;
    v.i = ((unsigned int)u) << 16;
    return v.f;
}

__device__ __forceinline__ void async16(const ushort* g, ushort* l) {
    __builtin_amdgcn_global_load_lds(
        (const __attribute__((address_space(1))) unsigned int*)g,
        (__attribute__((address_space(3))) unsigned int*)l, 16, 0, 0);
}

// ---------------- f32 -> (hi, lo) bf16 planes ----------------
__global__ __launch_bounds__(256)
void split_cvt(const float4* __restrict__ in, ushort4* __restrict__ hi,
               ushort4* __restrict__ lo, int n4) {
    int i = blockIdx.x * 256 + threadIdx.x;
    if (i >= n4) return;
    float4 v = in[i];
    ushort4 h, l;
    h.x = f2bf(v.x); l.x = f2bf(v.x - bf2f(h.x));
    h.y = f2bf(v.y); l.y = f2bf(v.y - bf2f(h.y));
    h.z = f2bf(v.z); l.z = f2bf(v.z - bf2f(h.z));
    h.w = f2bf(v.w); l.w = f2bf(v.w - bf2f(h.w));
    hi[i] = h; lo[i] = l;
}

// ---------------- MFMA GEMM: C[M,N] = A[M,K] @ B[N,K]^T (split bf16, ~f32 acc) ----
__global__ __launch_bounds__(256)
void gemm_mfma_split(const ushort* __restrict__ Ah, const ushort* __restrict__ Al,
                     const ushort* __restrict__ Bh, const ushort* __restrict__ Bl,
                     float* __restrict__ C, int K, int ldc) {
    __shared__ ushort sA[2][128][32];   // 16 KB
    __shared__ ushort sB[2][128][32];   // 16 KB
    const int tid  = threadIdx.x;
    const int wave = tid >> 6, lane = tid & 63;
    const int m0 = blockIdx.y * 128, n0 = blockIdx.x * 128;
    const int wm = (wave >> 1) * 64, wn = (wave & 1) * 64;
    const int srow = lane >> 2;
    const int scol = (lane & 3) * 8;

    f32x4 acc[4][4];
    #pragma unroll
    for (int i = 0; i < 4; i++)
        #pragma unroll
        for (int j = 0; j < 4; j++) acc[i][j] = (f32x4){0.f, 0.f, 0.f, 0.f};

    const int r0 = wave * 32;

    for (int k0 = 0; k0 < K; k0 += 32) {
        #pragma unroll
        for (int i = 0; i < 2; i++) {
            int rt = r0 + i * 16;
            int rg = rt + srow;
            size_t goffA = (size_t)(m0 + rg) * K + k0 + scol;
            size_t goffB = (size_t)(n0 + rg) * K + k0 + scol;
            async16(Ah + goffA, &sA[0][rt][0]);
            async16(Al + goffA, &sA[1][rt][0]);
            async16(Bh + goffB, &sB[0][rt][0]);
            async16(Bl + goffB, &sB[1][rt][0]);
        }
        __syncthreads();

        const int fr = lane & 15, fk = (lane >> 4) * 8;
        bf16x8 a[2][4], b[2][4];
        #pragma unroll
        for (int t = 0; t < 4; t++) {
            a[0][t] = *(const bf16x8*)&sA[0][wm + t * 16 + fr][fk];
            a[1][t] = *(const bf16x8*)&sA[1][wm + t * 16 + fr][fk];
            b[0][t] = *(const bf16x8*)&sB[0][wn + t * 16 + fr][fk];
            b[1][t] = *(const bf16x8*)&sB[1][wn + t * 16 + fr][fk];
        }
        #pragma unroll
        for (int mt = 0; mt < 4; mt++)
            #pragma unroll
            for (int nt = 0; nt < 4; nt++) {
                acc[mt][nt] = __builtin_amdgcn_mfma_f32_16x16x32_bf16(
                    a[0][mt], b[0][nt], acc[mt][nt], 0, 0, 0);
                acc[mt][nt] = __builtin_amdgcn_mfma_f32_16x16x32_bf16(
                    a[0][mt], b[1][nt], acc[mt][nt], 0, 0, 0);
                acc[mt][nt] = __builtin_amdgcn_mfma_f32_16x16x32_bf16(
                    a[1][mt], b[0][nt], acc[mt][nt], 0, 0, 0);
            }
        __syncthreads();
    }

    const int fr = lane & 15, rq = (lane >> 4) * 4;
    #pragma unroll
    for (int mt = 0; mt < 4; mt++)
        #pragma unroll
        for (int nt = 0; nt < 4; nt++) {
            int col = n0 + wn + nt * 16 + fr;
            int row = m0 + wm + mt * 16 + rq;
            #pragma unroll
            for (int r = 0; r < 4; r++)
                C[(size_t)(row + r) * ldc + col] = acc[mt][nt][r];
        }
}

// ---------------- conv (K=4 causal) + SiLU ----------------
__global__ __launch_bounds__(256)
void conv_silu(const float* __restrict__ xBC, const float* __restrict__ conv_w,
               float* __restrict__ out) {
    int idx = blockIdx.x * 256 + threadIdx.x;
    if (idx >= LSEQ * D_INNER) return;
    int t = idx / D_INNER, c = idx - t * D_INNER;
    float acc = 0.f;
    #pragma unroll
    for (int k = 0; k < KCONV; k++) {
        int tt = t - (KCONV - 1) + k;
        if (tt >= 0) acc += xBC[(size_t)tt * D_INNER + c] * conv_w[c * KCONV + k];
    }
    out[idx] = siluf(acc);
}

// ---------------- S1: softplus(dt)+cumsum (dt raw from combined zq buffer) ----
__global__ __launch_bounds__(1024)
void dt_scan(const float* __restrict__ zq,     // [L, NZ]; raw dt at col 4096+g
             const float* __restrict__ A_log, const float* __restrict__ dt_bias,
             float* __restrict__ dt_soft, float* __restrict__ Sbuf,
             float* __restrict__ Ebuf) {
    const int g = blockIdx.x, t = threadIdx.x;
    __shared__ float buf0[LSEQ], buf1[LSEQ];
    float dtr = zq[(size_t)t * NZ + D_SSM + g] + dt_bias[g];
    float dt = (dtr > 20.f) ? dtr : log1pf(expf(dtr));
    dt_soft[g * LSEQ + t] = dt;
    buf0[t] = dt;
    __syncthreads();
    float* src = buf0; float* dst = buf1;
    for (int off = 1; off < LSEQ; off <<= 1) {
        float v = src[t];
        if (t >= off) v += src[t - off];
        dst[t] = v;
        __syncthreads();
        float* tmp = src; src = dst; dst = tmp;
    }
    float A = -expf(A_log[g]);
    float S = A * src[t];
    Sbuf[g * LSEQ + t] = S;
    if ((t & (LC - 1)) == LC - 1) Ebuf[g * NC + (t >> 6)] = S;
}

// ---------------- S2: chunk states ----------------
__global__ __launch_bounds__(256)
void chunk_state(const float* __restrict__ xc, const float* __restrict__ dt_soft,
                 const float* __restrict__ Sbuf, const float* __restrict__ Ebuf,
                 float* __restrict__ Sc) {
    const int g = blockIdx.x, c = blockIdx.y;
    const int tid = threadIdx.x;
    const int t0 = c * LC;
    __shared__ __align__(16) float wB[LC][DS];
    __shared__ float Xs[LC][HD];
    __shared__ float sw[LC];

    if (tid < LC) {
        float Ec = Ebuf[g * NC + c];
        sw[tid] = expf(Ec - Sbuf[g * LSEQ + t0 + tid]) * dt_soft[g * LSEQ + t0 + tid];
    }
    __syncthreads();
    for (int i = tid; i < LC * DS; i += 256) {
        int r = i >> 6, s = i & 63;
        wB[r][s] = sw[r] * xc[(size_t)(t0 + r) * D_INNER + D_SSM + g * DS + s];
    }
    for (int i = tid; i < LC * HD; i += 256) {
        int r = i >> 7, h = i & 127;
        Xs[r][h] = xc[(size_t)(t0 + r) * D_INNER + g * HD + h];
    }
    __syncthreads();

    const int h = tid & 127, sh = (tid >> 7) * 32;
    float acc[32];
    #pragma unroll
    for (int j = 0; j < 32; j++) acc[j] = 0.f;
    for (int r = 0; r < LC; r++) {
        float xv = Xs[r][h];
        const float4* wrow = (const float4*)&wB[r][sh];
        #pragma unroll
        for (int q = 0; q < 8; q++) {
            float4 w4 = wrow[q];
            acc[4*q+0] += w4.x * xv;
            acc[4*q+1] += w4.y * xv;
            acc[4*q+2] += w4.z * xv;
            acc[4*q+3] += w4.w * xv;
        }
    }
    float* out = Sc + (size_t)(g * NC + c) * DS * HD;
    #pragma unroll
    for (int j = 0; j < 32; j++) out[(size_t)(sh + j) * HD + h] = acc[j];
}

// ---------------- S3: prefix over chunks ----------------
__global__ __launch_bounds__(256)
void chunk_prefix(const float* __restrict__ Sc, const float* __restrict__ Ebuf,
                  float* __restrict__ Hbuf) {
    const int g = blockIdx.y;
    const int e = blockIdx.x * 256 + threadIdx.x;
    float H = 0.f, Eprev = 0.f;
    for (int c = 0; c < NC; c++) {
        size_t base = (size_t)(g * NC + c) * DS * HD;
        Hbuf[base + e] = H;
        float Ec = Ebuf[g * NC + c];
        H = expf(Ec - Eprev) * H + Sc[base + e];
        Eprev = Ec;
    }
}

// ---------------- S4: per-chunk output + RMSNorm + SiLU(z), emits yg hi/lo bf16 ----
__global__ __launch_bounds__(256)
void chunk_output(const float* __restrict__ xc, const float* __restrict__ dt_soft,
                  const float* __restrict__ Sbuf, const float* __restrict__ Ebuf,
                  const float* __restrict__ Hbuf,
                  const float* __restrict__ zq,      // [L,NZ]: z cols 0..4095, D raw at 4128+g
                  const float* __restrict__ norm_w,
                  ushort* __restrict__ ygH, ushort* __restrict__ ygL) {
    const int g = blockIdx.x, c = blockIdx.y;
    const int tid = threadIdx.x;
    const int t0 = c * LC;

    __shared__ __align__(16) float smem[4096 + 4096 + 8192];
    float* CT = smem;
    float* BW = smem + 4096;
    float* Xs = smem + 8192;
    float* red = smem;
    float* sscale = smem + 256;

    for (int i = tid; i < LC * DS; i += 256) {
        int t = i >> 6, s = i & 63;
        CT[s * LC + t] = xc[(size_t)(t0 + t) * D_INNER + D_SSM + NG * DS + g * DS + s];
        BW[t * DS + s] = xc[(size_t)(t0 + t) * D_INNER + D_SSM + g * DS + s];
    }
    for (int i = tid; i < LC * HD; i += 256) {
        int t = i >> 7, h = i & 127;
        Xs[t * HD + h] = xc[(size_t)(t0 + t) * D_INNER + g * HD + h];
    }
    __syncthreads();

    {
        const int t = tid & 63, tau0 = tid >> 6;
        float Greg[16];
        #pragma unroll
        for (int k = 0; k < 16; k++) Greg[k] = 0.f;
        for (int s = 0; s < DS; s++) {
            float cv = CT[s * LC + t];
            #pragma unroll
            for (int k = 0; k < 16; k++) Greg[k] += cv * BW[(tau0 + 4 * k) * DS + s];
        }
        __syncthreads();
        float St = Sbuf[g * LSEQ + t0 + t];
        #pragma unroll
        for (int k = 0; k < 16; k++) {
            int tau = tau0 + 4 * k;
            float w = 0.f;
            if (tau <= t)
                w = expf(St - Sbuf[g * LSEQ + t0 + tau]) *
                    dt_soft[g * LSEQ + t0 + tau] * Greg[k];
            BW[tau * LC + t] = w;
        }
    }
    __syncthreads();

    const int h = tid & 127, tb = (tid >> 7) * 32;
    float y[32], T[32];
    #pragma unroll
    for (int j = 0; j < 32; j++) { y[j] = 0.f; T[j] = 0.f; }

    for (int tau = 0; tau < LC; tau++) {
        float xv = Xs[tau * HD + h];
        const float4* wrow = (const float4*)&BW[tau * LC + tb];
        #pragma unroll
        for (int q = 0; q < 8; q++) {
            float4 w4 = wrow[q];
            y[4*q+0] += w4.x * xv;
            y[4*q+1] += w4.y * xv;
            y[4*q+2] += w4.z * xv;
            y[4*q+3] += w4.w * xv;
        }
    }
    {
        const float* Hg = Hbuf + (size_t)(g * NC + c) * DS * HD;
        for (int s = 0; s < DS; s++) {
            float Hv = Hg[(size_t)s * HD + h];
            const float* crow = &CT[s * LC + tb];
            #pragma unroll
            for (int j = 0; j < 32; j++) T[j] += crow[j] * Hv;
        }
    }
    float Eprev = (c > 0) ? Ebuf[g * NC + c - 1] : 0.f;
    #pragma unroll
    for (int j = 0; j < 32; j++) {
        int t = tb + j;
        float St = Sbuf[g * LSEQ + t0 + t];
        float Dv = zq[(size_t)(t0 + t) * NZ + D_SSM + NG + g];
        y[j] += expf(St - Eprev) * T[j] + Dv * Xs[t * HD + h];
    }
    __syncthreads();
    #pragma unroll
    for (int j = 0; j < 32; j++) Xs[(tb + j) * HD + h] = y[j];
    __syncthreads();

    {
        int t = tid >> 2, q = tid & 3;
        float p = 0.f;
        for (int i = 0; i < 32; i++) {
            float v = Xs[t * HD + q * 32 + i];
            p += v * v;
        }
        red[t * 4 + q] = p;
    }
    __syncthreads();
    if (tid < LC) {
        float s2 = red[tid*4] + red[tid*4+1] + red[tid*4+2] + red[tid*4+3];
        sscale[tid] = rsqrtf(s2 * (1.f / HD) + EPS_RMS);
    }
    __syncthreads();

    float nw = norm_w[h];
    #pragma unroll
    for (int j = 0; j < 32; j++) {
        int t = tb + j;
        float zv = zq[(size_t)(t0 + t) * NZ + g * HD + h];
        size_t idx = (size_t)(t0 + t) * D_SSM + g * HD + h;
        float val = y[j] * sscale[t] * nw * siluf(zv);
        unsigned short hb = f2bf(val);
        ygH[idx] = hb;
        ygL[idx] = f2bf(val - bf2f(hb));
    }
}

extern "C" void kernel_launch(void* const* d_in, const int* in_sizes, int n_in,
                              void* d_out, int out_size, void* d_ws, size_t ws_size,
                              hipStream_t stream) {
    const float* hs      = (const float*)d_in[0];
    const float* W_qkv   = (const float*)d_in[1];
    const float* W_z     = (const float*)d_in[2];
    const float* W_a     = (const float*)d_in[3];
    const float* W_b     = (const float*)d_in[4];
    const float* conv_w  = (const float*)d_in[5];
    const float* W_out   = (const float*)d_in[6];
    const float* norm_w  = (const float*)d_in[7];
    const float* A_log   = (const float*)d_in[8];
    const float* dt_bias = (const float*)d_in[9];
    float* out = (float*)d_out;

    float* ws      = (float*)d_ws;
    float* xconv   = ws;                                   // 8388608
    float* zq      = xconv + (size_t)LSEQ * D_INNER;       // 1024*4224 = 4325376
    float* dt_soft = zq + (size_t)LSEQ * NZ;               // 32768
    float* Sbuf    = dt_soft + (size_t)NG * LSEQ;          // 32768
    float* Ebuf    = Sbuf + (size_t)NG * LSEQ;             // 512
    float* xBC     = Ebuf + NG * NC;                       // 8388608 (Sc+Hbuf alias)
    float* Sc      = xBC;
    float* Hbuf    = xBC + (size_t)NG * NC * DS * HD;
    ushort* hsH    = (ushort*)(xBC + (size_t)LSEQ * D_INNER);
    ushort* hsL    = hsH + (size_t)LSEQ * HID;             // 2621440 each
    ushort* WH     = hsL + (size_t)LSEQ * HID;             // 4224*2560 = 10813440 each
    ushort* WL     = WH + (size_t)NZ * HID;
    ushort* ygH    = WL + (size_t)NZ * HID;                // 4194304 each
    ushort* ygL    = ygH + (size_t)LSEQ * D_SSM;

    dim3 blk(256);
    const int nW4 = (4096 * HID) / 4;      // 4096-row weight chunk, in float4s
    const int nS4 = (NG * HID) / 4;        // 32-row weight chunk, in float4s

    // hs -> hi/lo planes
    split_cvt<<<dim3((LSEQ * HID / 4 + 255) / 256), blk, 0, stream>>>(
        (const float4*)hs, (ushort4*)hsH, (ushort4*)hsL, LSEQ * HID / 4);

    // qkv GEMM in two N=4096 halves (weight plane buffer reuse)
    for (int half = 0; half < 2; half++) {
        split_cvt<<<dim3((nW4 + 255) / 256), blk, 0, stream>>>(
            (const float4*)(W_qkv + (size_t)half * 4096 * HID),
            (ushort4*)WH, (ushort4*)WL, nW4);
        gemm_mfma_split<<<dim3(4096 / 128, LSEQ / 128), blk, 0, stream>>>(
            hsH, hsL, WH, WL, xBC + half * 4096, HID, D_INNER);
    }

    // combined z + dt + D GEMM: weight rows [0,4096)=W_z, [4096,4128)=W_b, [4128,4160)=W_a
    split_cvt<<<dim3((nW4 + 255) / 256), blk, 0, stream>>>(
        (const float4*)W_z, (ushort4*)WH, (ushort4*)WL, nW4);
    split_cvt<<<dim3((nS4 + 255) / 256), blk, 0, stream>>>(
        (const float4*)W_b,
        (ushort4*)(WH + (size_t)D_SSM * HID), (ushort4*)(WL + (size_t)D_SSM * HID), nS4);
    split_cvt<<<dim3((nS4 + 255) / 256), blk, 0, stream>>>(
        (const float4*)W_a,
        (ushort4*)(WH + (size_t)(D_SSM + NG) * HID),
        (ushort4*)(WL + (size_t)(D_SSM + NG) * HID), nS4);
    gemm_mfma_split<<<dim3(NZ / 128, LSEQ / 128), blk, 0, stream>>>(
        hsH, hsL, WH, WL, zq, HID, NZ);

    conv_silu<<<dim3((LSEQ * D_INNER) / 256), blk, 0, stream>>>(xBC, conv_w, xconv);

    dt_scan<<<dim3(NG), dim3(1024), 0, stream>>>(zq, A_log, dt_bias,
                                                 dt_soft, Sbuf, Ebuf);
    chunk_state<<<dim3(NG, NC), blk, 0, stream>>>(xconv, dt_soft, Sbuf, Ebuf, Sc);
    chunk_prefix<<<dim3(DS * HD / 256, NG), blk, 0, stream>>>(Sc, Ebuf, Hbuf);
    chunk_output<<<dim3(NG, NC), blk, 0, stream>>>(xconv, dt_soft, Sbuf, Ebuf,
                                                   Hbuf, zq, norm_w, ygH, ygL);

    // out = yg @ W_out^T  (M=1024, N=2560, K=4096)
    split_cvt<<<dim3((nW4 + 255) / 256), blk, 0, stream>>>(
        (const float4*)W_out, (ushort4*)WH, (ushort4*)WL, nW4);
    gemm_mfma_split<<<dim3(HID / 128, LSEQ / 128), blk, 0, stream>>>(
        ygH, ygL, WH, WL, out, D_SSM, HID);
}

// Round 6
// 738.768 us; speedup vs baseline: 6.6903x; 1.1490x over previous
//
#include <hip/hip_runtime.h>
#include <hip/hip_bf16.h>
#include <math.h>

#define HID     2560
#define D_INNER 8192
#define NG      32
#define D_SSM   4096
#define KCONV   4
#define HD      128
#define DS      64
#define LSEQ    1024
#define LC      64
#define NC      (LSEQ / LC)
#define NZ      4224          // z(4096) + dt(32) + D(32) + pad(64)
#define NBIG    12416         // qkv(8192) + NZ
#define EPS_RMS 1e-6f

typedef short bf16x8 __attribute__((ext_vector_type(8)));
typedef float f32x4 __attribute__((ext_vector_type(4)));

__device__ __forceinline__ float siluf(float x) { return x / (1.f + expf(-x)); }

__device__ __forceinline__ unsigned short f2bf(float x) {
    __hip_bfloat16 b = __float2bfloat16(x);
    return *reinterpret_cast<unsigned short*>(&b);
}
__device__ __forceinline__ float bf2f(unsigned short u) {
    union { unsigned int i; float f; } v;
    v.i = ((unsigned int)u) << 16;
    return v.f;
}

__device__ __forceinline__ void async16(const ushort* g, ushort* l) {
    __builtin_amdgcn_global_load_lds(
        (const __attribute__((address_space(1))) unsigned int*)g,
        (__attribute__((address_space(3))) unsigned int*)l, 16, 0, 0);
}

// ---------------- f32 -> (hi, lo) bf16 planes ----------------
__global__ __launch_bounds__(256)
void split_cvt(const float4* __restrict__ in, ushort4* __restrict__ hi,
               ushort4* __restrict__ lo, int n4) {
    int i = blockIdx.x * 256 + threadIdx.x;
    if (i >= n4) return;
    float4 v = in[i];
    ushort4 h, l;
    h.x = f2bf(v.x); l.x = f2bf(v.x - bf2f(h.x));
    h.y = f2bf(v.y); l.y = f2bf(v.y - bf2f(h.y));
    h.z = f2bf(v.z); l.z = f2bf(v.z - bf2f(h.z));
    h.w = f2bf(v.w); l.w = f2bf(v.w - bf2f(h.w));
    hi[i] = h; lo[i] = l;
}

// ---------------- shared MFMA mainloop: 128x128 tile, split bf16, 3-term ----
__device__ __forceinline__ void mfma_core(
    const ushort* __restrict__ Ah, const ushort* __restrict__ Al,
    const ushort* __restrict__ Bh, const ushort* __restrict__ Bl,
    int lda, int ldb, int m0, int n0, int kBeg, int kEnd,
    ushort (&sA)[2][128][32], ushort (&sB)[2][128][32],
    f32x4 (&acc)[4][4], int tid)
{
    const int wave = tid >> 6, lane = tid & 63;
    const int wm = (wave >> 1) * 64, wn = (wave & 1) * 64;
    const int srow = lane >> 2;
    const int scol = (lane & 3) * 8;
    const int r0 = wave * 32;

    for (int k0 = kBeg; k0 < kEnd; k0 += 32) {
        #pragma unroll
        for (int i = 0; i < 2; i++) {
            int rt = r0 + i * 16;
            int rg = rt + srow;
            size_t goffA = (size_t)(m0 + rg) * lda + k0 + scol;
            size_t goffB = (size_t)(n0 + rg) * ldb + k0 + scol;
            async16(Ah + goffA, &sA[0][rt][0]);
            async16(Al + goffA, &sA[1][rt][0]);
            async16(Bh + goffB, &sB[0][rt][0]);
            async16(Bl + goffB, &sB[1][rt][0]);
        }
        __syncthreads();

        const int fr = lane & 15, fk = (lane >> 4) * 8;
        bf16x8 a[2][4], b[2][4];
        #pragma unroll
        for (int t = 0; t < 4; t++) {
            a[0][t] = *(const bf16x8*)&sA[0][wm + t * 16 + fr][fk];
            a[1][t] = *(const bf16x8*)&sA[1][wm + t * 16 + fr][fk];
            b[0][t] = *(const bf16x8*)&sB[0][wn + t * 16 + fr][fk];
            b[1][t] = *(const bf16x8*)&sB[1][wn + t * 16 + fr][fk];
        }
        #pragma unroll
        for (int mt = 0; mt < 4; mt++)
            #pragma unroll
            for (int nt = 0; nt < 4; nt++) {
                acc[mt][nt] = __builtin_amdgcn_mfma_f32_16x16x32_bf16(
                    a[0][mt], b[0][nt], acc[mt][nt], 0, 0, 0);
                acc[mt][nt] = __builtin_amdgcn_mfma_f32_16x16x32_bf16(
                    a[0][mt], b[1][nt], acc[mt][nt], 0, 0, 0);
                acc[mt][nt] = __builtin_amdgcn_mfma_f32_16x16x32_bf16(
                    a[1][mt], b[0][nt], acc[mt][nt], 0, 0, 0);
            }
        __syncthreads();
    }
}

// ---------------- big GEMM: [1024, NBIG] = hs @ [Wqkv|Wz|Wb|Wa]^T ----------------
// cols 0..8191 -> xBC (ldc 8192), cols 8192.. -> zq (ldc NZ)
__global__ __launch_bounds__(256)
void gemm_big(const ushort* __restrict__ Ah, const ushort* __restrict__ Al,
              const ushort* __restrict__ Bh, const ushort* __restrict__ Bl,
              float* __restrict__ xBC, float* __restrict__ zq) {
    __shared__ ushort sA[2][128][32];
    __shared__ ushort sB[2][128][32];
    const int tid = threadIdx.x;
    const int m0 = blockIdx.y * 128, n0 = blockIdx.x * 128;

    f32x4 acc[4][4];
    #pragma unroll
    for (int i = 0; i < 4; i++)
        #pragma unroll
        for (int j = 0; j < 4; j++) acc[i][j] = (f32x4){0.f, 0.f, 0.f, 0.f};

    mfma_core(Ah, Al, Bh, Bl, HID, HID, m0, n0, 0, HID, sA, sB, acc, tid);

    const int wave = tid >> 6, lane = tid & 63;
    const int wm = (wave >> 1) * 64, wn = (wave & 1) * 64;
    const int fr = lane & 15, rq = (lane >> 4) * 4;
    float* base; int ldc, cofs;
    if (n0 < 8192) { base = xBC; ldc = 8192; cofs = 0; }
    else           { base = zq;  ldc = NZ;   cofs = 8192; }
    #pragma unroll
    for (int mt = 0; mt < 4; mt++)
        #pragma unroll
        for (int nt = 0; nt < 4; nt++) {
            int col = n0 + wn + nt * 16 + fr - cofs;
            int row = m0 + wm + mt * 16 + rq;
            #pragma unroll
            for (int r = 0; r < 4; r++)
                base[(size_t)(row + r) * ldc + col] = acc[mt][nt][r];
        }
}

// ---------------- out GEMM, split-K x4, atomic accumulate ----------------
__global__ __launch_bounds__(256)
void gemm_out_splitk(const ushort* __restrict__ Ah, const ushort* __restrict__ Al,
                     const ushort* __restrict__ Bh, const ushort* __restrict__ Bl,
                     float* __restrict__ C) {
    __shared__ ushort sA[2][128][32];
    __shared__ ushort sB[2][128][32];
    const int tid = threadIdx.x;
    const int m0 = blockIdx.y * 128, n0 = blockIdx.x * 128;
    const int kBeg = blockIdx.z * (D_SSM / 4), kEnd = kBeg + D_SSM / 4;

    f32x4 acc[4][4];
    #pragma unroll
    for (int i = 0; i < 4; i++)
        #pragma unroll
        for (int j = 0; j < 4; j++) acc[i][j] = (f32x4){0.f, 0.f, 0.f, 0.f};

    mfma_core(Ah, Al, Bh, Bl, D_SSM, D_SSM, m0, n0, kBeg, kEnd, sA, sB, acc, tid);

    const int wave = tid >> 6, lane = tid & 63;
    const int wm = (wave >> 1) * 64, wn = (wave & 1) * 64;
    const int fr = lane & 15, rq = (lane >> 4) * 4;
    #pragma unroll
    for (int mt = 0; mt < 4; mt++)
        #pragma unroll
        for (int nt = 0; nt < 4; nt++) {
            int col = n0 + wn + nt * 16 + fr;
            int row = m0 + wm + mt * 16 + rq;
            #pragma unroll
            for (int r = 0; r < 4; r++)
                atomicAdd(&C[(size_t)(row + r) * HID + col], acc[mt][nt][r]);
        }
}

// ---------------- conv (K=4 causal) + SiLU ----------------
__global__ __launch_bounds__(256)
void conv_silu(const float* __restrict__ xBC, const float* __restrict__ conv_w,
               float* __restrict__ out) {
    int idx = blockIdx.x * 256 + threadIdx.x;
    if (idx >= LSEQ * D_INNER) return;
    int t = idx / D_INNER, c = idx - t * D_INNER;
    float acc = 0.f;
    #pragma unroll
    for (int k = 0; k < KCONV; k++) {
        int tt = t - (KCONV - 1) + k;
        if (tt >= 0) acc += xBC[(size_t)tt * D_INNER + c] * conv_w[c * KCONV + k];
    }
    out[idx] = siluf(acc);
}

// ---------------- S1: softplus(dt)+cumsum ----------------
__global__ __launch_bounds__(1024)
void dt_scan(const float* __restrict__ zq,
             const float* __restrict__ A_log, const float* __restrict__ dt_bias,
             float* __restrict__ dt_soft, float* __restrict__ Sbuf,
             float* __restrict__ Ebuf) {
    const int g = blockIdx.x, t = threadIdx.x;
    __shared__ float buf0[LSEQ], buf1[LSEQ];
    float dtr = zq[(size_t)t * NZ + D_SSM + g] + dt_bias[g];
    float dt = (dtr > 20.f) ? dtr : log1pf(expf(dtr));
    dt_soft[g * LSEQ + t] = dt;
    buf0[t] = dt;
    __syncthreads();
    float* src = buf0; float* dst = buf1;
    for (int off = 1; off < LSEQ; off <<= 1) {
        float v = src[t];
        if (t >= off) v += src[t - off];
        dst[t] = v;
        __syncthreads();
        float* tmp = src; src = dst; dst = tmp;
    }
    float A = -expf(A_log[g]);
    float S = A * src[t];
    Sbuf[g * LSEQ + t] = S;
    if ((t & (LC - 1)) == LC - 1) Ebuf[g * NC + (t >> 6)] = S;
}

// ---------------- S2: chunk states ----------------
__global__ __launch_bounds__(256)
void chunk_state(const float* __restrict__ xc, const float* __restrict__ dt_soft,
                 const float* __restrict__ Sbuf, const float* __restrict__ Ebuf,
                 float* __restrict__ Sc) {
    const int g = blockIdx.x, c = blockIdx.y;
    const int tid = threadIdx.x;
    const int t0 = c * LC;
    __shared__ __align__(16) float wB[LC][DS];
    __shared__ float Xs[LC][HD];
    __shared__ float sw[LC];

    if (tid < LC) {
        float Ec = Ebuf[g * NC + c];
        sw[tid] = expf(Ec - Sbuf[g * LSEQ + t0 + tid]) * dt_soft[g * LSEQ + t0 + tid];
    }
    __syncthreads();
    for (int i = tid; i < LC * DS; i += 256) {
        int r = i >> 6, s = i & 63;
        wB[r][s] = sw[r] * xc[(size_t)(t0 + r) * D_INNER + D_SSM + g * DS + s];
    }
    for (int i = tid; i < LC * HD; i += 256) {
        int r = i >> 7, h = i & 127;
        Xs[r][h] = xc[(size_t)(t0 + r) * D_INNER + g * HD + h];
    }
    __syncthreads();

    const int h = tid & 127, sh = (tid >> 7) * 32;
    float acc[32];
    #pragma unroll
    for (int j = 0; j < 32; j++) acc[j] = 0.f;
    for (int r = 0; r < LC; r++) {
        float xv = Xs[r][h];
        const float4* wrow = (const float4*)&wB[r][sh];
        #pragma unroll
        for (int q = 0; q < 8; q++) {
            float4 w4 = wrow[q];
            acc[4*q+0] += w4.x * xv;
            acc[4*q+1] += w4.y * xv;
            acc[4*q+2] += w4.z * xv;
            acc[4*q+3] += w4.w * xv;
        }
    }
    float* out = Sc + (size_t)(g * NC + c) * DS * HD;
    #pragma unroll
    for (int j = 0; j < 32; j++) out[(size_t)(sh + j) * HD + h] = acc[j];
}

// ---------------- S3: prefix over chunks ----------------
__global__ __launch_bounds__(256)
void chunk_prefix(const float* __restrict__ Sc, const float* __restrict__ Ebuf,
                  float* __restrict__ Hbuf) {
    const int g = blockIdx.y;
    const int e = blockIdx.x * 256 + threadIdx.x;
    float H = 0.f, Eprev = 0.f;
    for (int c = 0; c < NC; c++) {
        size_t base = (size_t)(g * NC + c) * DS * HD;
        Hbuf[base + e] = H;
        float Ec = Ebuf[g * NC + c];
        H = expf(Ec - Eprev) * H + Sc[base + e];
        Eprev = Ec;
    }
}

// ---------------- S4: per-chunk output + RMSNorm + SiLU(z), emits yg hi/lo ----
__global__ __launch_bounds__(256)
void chunk_output(const float* __restrict__ xc, const float* __restrict__ dt_soft,
                  const float* __restrict__ Sbuf, const float* __restrict__ Ebuf,
                  const float* __restrict__ Hbuf,
                  const float* __restrict__ zq, const float* __restrict__ norm_w,
                  ushort* __restrict__ ygH, ushort* __restrict__ ygL) {
    const int g = blockIdx.x, c = blockIdx.y;
    const int tid = threadIdx.x;
    const int t0 = c * LC;

    __shared__ __align__(16) float smem[4096 + 4096 + 8192];
    float* CT = smem;
    float* BW = smem + 4096;
    float* Xs = smem + 8192;
    float* red = smem;
    float* sscale = smem + 256;

    for (int i = tid; i < LC * DS; i += 256) {
        int t = i >> 6, s = i & 63;
        CT[s * LC + t] = xc[(size_t)(t0 + t) * D_INNER + D_SSM + NG * DS + g * DS + s];
        BW[t * DS + s] = xc[(size_t)(t0 + t) * D_INNER + D_SSM + g * DS + s];
    }
    for (int i = tid; i < LC * HD; i += 256) {
        int t = i >> 7, h = i & 127;
        Xs[t * HD + h] = xc[(size_t)(t0 + t) * D_INNER + g * HD + h];
    }
    __syncthreads();

    {
        const int t = tid & 63, tau0 = tid >> 6;
        float Greg[16];
        #pragma unroll
        for (int k = 0; k < 16; k++) Greg[k] = 0.f;
        for (int s = 0; s < DS; s++) {
            float cv = CT[s * LC + t];
            #pragma unroll
            for (int k = 0; k < 16; k++) Greg[k] += cv * BW[(tau0 + 4 * k) * DS + s];
        }
        __syncthreads();
        float St = Sbuf[g * LSEQ + t0 + t];
        #pragma unroll
        for (int k = 0; k < 16; k++) {
            int tau = tau0 + 4 * k;
            float w = 0.f;
            if (tau <= t)
                w = expf(St - Sbuf[g * LSEQ + t0 + tau]) *
                    dt_soft[g * LSEQ + t0 + tau] * Greg[k];
            BW[tau * LC + t] = w;
        }
    }
    __syncthreads();

    const int h = tid & 127, tb = (tid >> 7) * 32;
    float y[32], T[32];
    #pragma unroll
    for (int j = 0; j < 32; j++) { y[j] = 0.f; T[j] = 0.f; }

    for (int tau = 0; tau < LC; tau++) {
        float xv = Xs[tau * HD + h];
        const float4* wrow = (const float4*)&BW[tau * LC + tb];
        #pragma unroll
        for (int q = 0; q < 8; q++) {
            float4 w4 = wrow[q];
            y[4*q+0] += w4.x * xv;
            y[4*q+1] += w4.y * xv;
            y[4*q+2] += w4.z * xv;
            y[4*q+3] += w4.w * xv;
        }
    }
    {
        const float* Hg = Hbuf + (size_t)(g * NC + c) * DS * HD;
        for (int s = 0; s < DS; s++) {
            float Hv = Hg[(size_t)s * HD + h];
            const float* crow = &CT[s * LC + tb];
            #pragma unroll
            for (int j = 0; j < 32; j++) T[j] += crow[j] * Hv;
        }
    }
    float Eprev = (c > 0) ? Ebuf[g * NC + c - 1] : 0.f;
    #pragma unroll
    for (int j = 0; j < 32; j++) {
        int t = tb + j;
        float St = Sbuf[g * LSEQ + t0 + t];
        float Dv = zq[(size_t)(t0 + t) * NZ + D_SSM + NG + g];
        y[j] += expf(St - Eprev) * T[j] + Dv * Xs[t * HD + h];
    }
    __syncthreads();
    #pragma unroll
    for (int j = 0; j < 32; j++) Xs[(tb + j) * HD + h] = y[j];
    __syncthreads();

    {
        int t = tid >> 2, q = tid & 3;
        float p = 0.f;
        for (int i = 0; i < 32; i++) {
            float v = Xs[t * HD + q * 32 + i];
            p += v * v;
        }
        red[t * 4 + q] = p;
    }
    __syncthreads();
    if (tid < LC) {
        float s2 = red[tid*4] + red[tid*4+1] + red[tid*4+2] + red[tid*4+3];
        sscale[tid] = rsqrtf(s2 * (1.f / HD) + EPS_RMS);
    }
    __syncthreads();

    float nw = norm_w[h];
    #pragma unroll
    for (int j = 0; j < 32; j++) {
        int t = tb + j;
        float zv = zq[(size_t)(t0 + t) * NZ + g * HD + h];
        size_t idx = (size_t)(t0 + t) * D_SSM + g * HD + h;
        float val = y[j] * sscale[t] * nw * siluf(zv);
        unsigned short hb = f2bf(val);
        ygH[idx] = hb;
        ygL[idx] = f2bf(val - bf2f(hb));
    }
}

extern "C" void kernel_launch(void* const* d_in, const int* in_sizes, int n_in,
                              void* d_out, int out_size, void* d_ws, size_t ws_size,
                              hipStream_t stream) {
    const float* hs      = (const float*)d_in[0];
    const float* W_qkv   = (const float*)d_in[1];
    const float* W_z     = (const float*)d_in[2];
    const float* W_a     = (const float*)d_in[3];
    const float* W_b     = (const float*)d_in[4];
    const float* conv_w  = (const float*)d_in[5];
    const float* W_out   = (const float*)d_in[6];
    const float* norm_w  = (const float*)d_in[7];
    const float* A_log   = (const float*)d_in[8];
    const float* dt_bias = (const float*)d_in[9];
    float* out = (float*)d_out;

    float* ws      = (float*)d_ws;
    float* xBC     = ws;                                   // 8,388,608 f
    float* zq      = xBC + (size_t)LSEQ * D_INNER;         // 4,325,376 f
    float* dt_soft = zq + (size_t)LSEQ * NZ;               // 32768 f
    float* Sbuf    = dt_soft + (size_t)NG * LSEQ;          // 32768 f
    float* Ebuf    = Sbuf + (size_t)NG * LSEQ;             // 512 f
    ushort* hsH    = (ushort*)(Ebuf + 512);                // 2,621,440 us
    ushort* hsL    = hsH + (size_t)LSEQ * HID;
    ushort* WH     = hsL + (size_t)LSEQ * HID;             // NBIG*HID = 31,784,960 us
    ushort* WL     = WH + (size_t)NBIG * HID;
    // phase-2 overlay on WH/WL region (dead after gemm_big):
    float* xconv   = (float*)WH;                           // 8,388,608 f
    float* Sc      = xconv + (size_t)LSEQ * D_INNER;       // 4,194,304 f
    float* Hbuf    = Sc + (size_t)NG * NC * DS * HD;       // 4,194,304 f
    ushort* ygH    = (ushort*)(Hbuf + (size_t)NG * NC * DS * HD);  // 4,194,304 us
    ushort* ygL    = ygH + (size_t)LSEQ * D_SSM;
    ushort* WoH    = ygL + (size_t)LSEQ * D_SSM;           // 10,485,760 us
    ushort* WoL    = WoH + (size_t)HID * D_SSM;

    dim3 blk(256);

    // input/weight planes
    split_cvt<<<dim3((LSEQ * HID / 4 + 255) / 256), blk, 0, stream>>>(
        (const float4*)hs, (ushort4*)hsH, (ushort4*)hsL, LSEQ * HID / 4);
    split_cvt<<<dim3(((D_INNER * HID) / 4 + 255) / 256), blk, 0, stream>>>(
        (const float4*)W_qkv, (ushort4*)WH, (ushort4*)WL, (D_INNER * HID) / 4);
    split_cvt<<<dim3(((D_SSM * HID) / 4 + 255) / 256), blk, 0, stream>>>(
        (const float4*)W_z,
        (ushort4*)(WH + (size_t)D_INNER * HID), (ushort4*)(WL + (size_t)D_INNER * HID),
        (D_SSM * HID) / 4);
    split_cvt<<<dim3(((NG * HID) / 4 + 255) / 256), blk, 0, stream>>>(
        (const float4*)W_b,
        (ushort4*)(WH + (size_t)(D_INNER + D_SSM) * HID),
        (ushort4*)(WL + (size_t)(D_INNER + D_SSM) * HID), (NG * HID) / 4);
    split_cvt<<<dim3(((NG * HID) / 4 + 255) / 256), blk, 0, stream>>>(
        (const float4*)W_a,
        (ushort4*)(WH + (size_t)(D_INNER + D_SSM + NG) * HID),
        (ushort4*)(WL + (size_t)(D_INNER + D_SSM + NG) * HID), (NG * HID) / 4);

    // one merged projection GEMM: 776 blocks (~3/CU)
    gemm_big<<<dim3(NBIG / 128, LSEQ / 128), blk, 0, stream>>>(
        hsH, hsL, WH, WL, xBC, zq);

    conv_silu<<<dim3((LSEQ * D_INNER) / 256), blk, 0, stream>>>(xBC, conv_w, xconv);

    dt_scan<<<dim3(NG), dim3(1024), 0, stream>>>(zq, A_log, dt_bias,
                                                 dt_soft, Sbuf, Ebuf);
    chunk_state<<<dim3(NG, NC), blk, 0, stream>>>(xconv, dt_soft, Sbuf, Ebuf, Sc);
    chunk_prefix<<<dim3(DS * HD / 256, NG), blk, 0, stream>>>(Sc, Ebuf, Hbuf);
    chunk_output<<<dim3(NG, NC), blk, 0, stream>>>(xconv, dt_soft, Sbuf, Ebuf,
                                                   Hbuf, zq, norm_w, ygH, ygL);

    // out = yg @ W_out^T, split-K x4 with atomic accumulate
    split_cvt<<<dim3(((HID * D_SSM) / 4 + 255) / 256), blk, 0, stream>>>(
        (const float4*)W_out, (ushort4*)WoH, (ushort4*)WoL, (HID * D_SSM) / 4);
    hipMemsetAsync(out, 0, (size_t)LSEQ * HID * sizeof(float), stream);
    gemm_out_splitk<<<dim3(HID / 128, LSEQ / 128, 4), blk, 0, stream>>>(
        ygH, ygL, WoH, WoL, out);
}